// Round 6
// baseline (113.420 us; speedup 1.0000x reference)
//
#include <hip/hip_runtime.h>
#include <math.h>

#define NOUT   10
#define ROWLEN 784           // 28*28
#define WTOT   (NOUT*ROWLEN) // 7840

// ---------------------------------------------------------------------------
// Prep: fold conv+quantum+linear into Weff (10x784) + bias, into d_ws.
// ---------------------------------------------------------------------------
__global__ __launch_bounds__(256)
void quanv_prep(const float* __restrict__ conv_w, // (4,1,2,2)
                const float* __restrict__ conv_b, // (4,)
                const float* __restrict__ q_w,    // (4,4) (out,in)
                const float* __restrict__ lin_w,  // (10,1568)
                const float* __restrict__ lin_b,  // (10,)
                float* __restrict__ W)            // ws: [7840 W][10 bias]
{
    const int t = threadIdx.x;

    for (int idx = blockIdx.x * 256 + t; idx < WTOT; idx += gridDim.x * 256) {
        const int o = idx / ROWLEN;
        const int j = idx - o * ROWLEN;          // pixel h*28+w
        const int h = j / 28, w = j - h * 28;
        const int p = (h >> 1) * 14 + (w >> 1);  // patch index (196)
        const int k = (h & 1) * 2 + (w & 1);     // pos in 2x2 patch
        float s = 0.f;
        #pragma unroll
        for (int c = 0; c < 4; ++c)              // conv branch
            s += conv_w[c * 4 + k] * lin_w[o * 1568 + c * 196 + p];
        #pragma unroll
        for (int q = 0; q < 4; ++q)              // quantum branch
            s += q_w[q * 4 + k] * lin_w[o * 1568 + 784 + p * 4 + q];
        W[idx] = s;
    }

    if (blockIdx.x == 0) {
        __shared__ float rs[40];                 // rowsum[o][c]
        const int lane = t & 7;
        for (int pair = t >> 3; pair < 40; pair += 32) {
            const int o = pair >> 2, c = pair & 3;
            const float* base = lin_w + o * 1568 + c * 196;
            float s = 0.f;
            #pragma unroll
            for (int p = 0; p < 196; p += 8) {
                const int pp = p + lane;
                if (pp < 196) s += base[pp];
            }
            s += __shfl_xor(s, 1);
            s += __shfl_xor(s, 2);
            s += __shfl_xor(s, 4);
            if (lane == 0) rs[pair] = s;
        }
        __syncthreads();
        if (t < NOUT) {
            float s = lin_b[t];
            #pragma unroll
            for (int c = 0; c < 4; ++c) s += conv_b[c] * rs[t * 4 + c];
            W[WTOT + t] = s;
        }
    }
}

// ---------------------------------------------------------------------------
// Main. K2xO2 wave geometry for full occupancy:
//   wave = 4 rows; its four 16-lane groups split (K-half kh) x (out-half oh).
//   Each group: 5 outputs, 392 K-elements, 4 rows -> acc[4][5].
//   W amortized over 4 rows (same LDS traffic as R5), but threads double.
// Block = 1024 thr (16 waves) = 64 rows; grid = 512 = 2 blocks/CU:
//   LDS 2*31.4KB = 62.8KB, 32 waves/CU (100% slots). VGPR must be <= 64.
// ---------------------------------------------------------------------------
__global__ __launch_bounds__(1024, 8)
void quanv_main(const float* __restrict__ x,
                const float* __restrict__ Wg,   // ws
                float* __restrict__ out)
{
    __shared__ float Wl[WTOT];
    __shared__ float bias[NOUT];

    const int t    = threadIdx.x;
    const int lane = t & 63;
    const int wv   = t >> 6;           // wave in block, 0..15
    const int l    = lane & 15;        // lane in 16-group
    const int g2   = lane >> 4;        // group 0..3
    const int oh   = g2 & 1;           // output-half: 0 -> outs 0-4, 1 -> 5-9
    const int kh   = g2 >> 1;          // K-half: 0 -> floats 0-391, 1 -> 392-783
    const int r0   = blockIdx.x * 64 + wv * 4;

    const float* __restrict__ xr = x + (size_t)r0 * ROWLEN + kh * 392;

    // issue initial x prefetch BEFORE the LDS fill (independent work)
    float4 px0[4], px1[4];
    #pragma unroll
    for (int r = 0; r < 4; ++r) {
        px0[r] = *(const float4*)(xr + r * ROWLEN + 4 * l);
        px1[r] = *(const float4*)(xr + r * ROWLEN + 4 * l + 64);
    }

    {   // coalesced LDS fill: 1960 float4 over 1024 threads
        const float4* __restrict__ src = (const float4*)Wg;
        float4* dst = (float4*)Wl;
        #pragma unroll
        for (int i = 0; i < 2; ++i) {
            const int idx = t + 1024 * i;
            if (idx < WTOT / 4) dst[idx] = src[idx];
        }
        if (t < NOUT) bias[t] = Wg[WTOT + t];
    }
    __syncthreads();

    float acc[4][5];
    #pragma unroll
    for (int r = 0; r < 4; ++r)
        #pragma unroll
        for (int o = 0; o < 5; ++o) acc[r][o] = 0.f;

    const int wb = oh * 5 * ROWLEN + kh * 392;   // this group's W base (floats)

    // K-half = 392 floats = 98 float4: 6 full iters (16 chunks each) + 2-chunk tail
    #pragma unroll
    for (int i = 0; i < 6; ++i) {
        float4 cur[4];
        #pragma unroll
        for (int r = 0; r < 4; ++r) cur[r] = ((i & 1) == 0) ? px0[r] : px1[r];

        const int ni = i + 2;                    // depth-2 prefetch
        if (ni < 6) {
            const int nfo = 4 * l + 64 * ni;
            #pragma unroll
            for (int r = 0; r < 4; ++r) {
                const float4 v = *(const float4*)(xr + r * ROWLEN + nfo);
                if ((i & 1) == 0) px0[r] = v; else px1[r] = v;
            }
        } else if (ni == 6) {                    // i==4 (parity 0) -> tail into px0
            const int tfo = 384 + 4 * (l & 1);
            #pragma unroll
            for (int r = 0; r < 4; ++r)
                px0[r] = *(const float4*)(xr + r * ROWLEN + tfo);
        }

        const int fo = 4 * l + 64 * i;
        #pragma unroll
        for (int o = 0; o < 5; ++o) {
            const float4 w4 = *(const float4*)&Wl[wb + o * ROWLEN + fo];
            #pragma unroll
            for (int r = 0; r < 4; ++r)
                acc[r][o] = fmaf(cur[r].x, w4.x, fmaf(cur[r].y, w4.y,
                            fmaf(cur[r].z, w4.z, fmaf(cur[r].w, w4.w, acc[r][o]))));
        }
    }
    // tail: relative floats 384..391 (in px0); lanes 0..1 only
    if (l < 2) {
        const int fo = 384 + 4 * l;
        #pragma unroll
        for (int o = 0; o < 5; ++o) {
            const float4 w4 = *(const float4*)&Wl[wb + o * ROWLEN + fo];
            #pragma unroll
            for (int r = 0; r < 4; ++r)
                acc[r][o] = fmaf(px0[r].x, w4.x, fmaf(px0[r].y, w4.y,
                            fmaf(px0[r].z, w4.z, fmaf(px0[r].w, w4.w, acc[r][o]))));
        }
    }

    // group-internal butterfly (16 lanes), then K-combine across pairs (xor 32)
    #pragma unroll
    for (int r = 0; r < 4; ++r)
        #pragma unroll
        for (int o = 0; o < 5; ++o) {
            acc[r][o] += __shfl_xor(acc[r][o], 1);
            acc[r][o] += __shfl_xor(acc[r][o], 2);
            acc[r][o] += __shfl_xor(acc[r][o], 4);
            acc[r][o] += __shfl_xor(acc[r][o], 8);
            acc[r][o] += __shfl_xor(acc[r][o], 32);   // K-halves
        }

    // add own-half bias; exchange with output-half partner (xor 16)
    float own[4][5], ex[4][5];
    #pragma unroll
    for (int r = 0; r < 4; ++r)
        #pragma unroll
        for (int o = 0; o < 5; ++o) {
            own[r][o] = acc[r][o] + bias[oh * 5 + o];
            ex[r][o]  = __shfl_xor(own[r][o], 16);
        }

    // group g2 finishes row r0+g2. Select that row's values with
    // compile-time-indexed cndmask chains (no runtime register indexing).
    float lg[NOUT];
    #pragma unroll
    for (int o = 0; o < 5; ++o) {
        float osel = own[0][o];
        osel = (g2 == 1) ? own[1][o] : osel;
        osel = (g2 == 2) ? own[2][o] : osel;
        osel = (g2 == 3) ? own[3][o] : osel;
        float esel = ex[0][o];
        esel = (g2 == 1) ? ex[1][o] : esel;
        esel = (g2 == 2) ? ex[2][o] : esel;
        esel = (g2 == 3) ? ex[3][o] : esel;
        lg[o]     = oh ? esel : osel;     // outputs 0-4
        lg[o + 5] = oh ? osel : esel;     // outputs 5-9
    }

    float m = -1e30f;
    #pragma unroll
    for (int o = 0; o < NOUT; ++o) m = fmaxf(m, lg[o]);
    float s = 0.f;
    #pragma unroll
    for (int o = 0; o < NOUT; ++o) s += expf(lg[o] - m);
    const float lse = m + logf(s);

    if (l < NOUT) {
        float v = lg[0];
        #pragma unroll
        for (int o = 1; o < NOUT; ++o) v = (l == o) ? lg[o] : v;
        out[(size_t)(r0 + g2) * NOUT + l] = v - lse;
    }
}

extern "C" void kernel_launch(void* const* d_in, const int* in_sizes, int n_in,
                              void* d_out, int out_size, void* d_ws, size_t ws_size,
                              hipStream_t stream) {
    const float* x      = (const float*)d_in[0];
    const float* conv_w = (const float*)d_in[1];
    const float* conv_b = (const float*)d_in[2];
    const float* q_w    = (const float*)d_in[3];
    const float* lin_w  = (const float*)d_in[4];
    const float* lin_b  = (const float*)d_in[5];
    float* out = (float*)d_out;
    float* W   = (float*)d_ws;   // 7850 floats = 31.4 KB

    const int rows = in_sizes[0] / ROWLEN;   // 32768

    quanv_prep<<<31, 256, 0, stream>>>(conv_w, conv_b, q_w, lin_w, lin_b, W);
    quanv_main<<<rows / 64, 1024, 0, stream>>>(x, W, out);
}

// Round 8
// 35.495 us; speedup vs baseline: 3.1954x; 3.1954x over previous
//
#include <hip/hip_runtime.h>
#include <math.h>

#define NOUT   10
#define ROWLEN 784           // 28*28
#define WTOT   (NOUT*ROWLEN) // 7840

// ws layout: [7840 x ushort bf16 W][10 x float bias @ +15680B]
// bf16 W: |W|~0.03, rel err 2^-9 -> logit error ~3e-3, threshold 0.1525.

// ---------------------------------------------------------------------------
// Prep: fold conv+quantum+linear into Weff (10x784, bf16 RNE) + fp32 bias.
// ---------------------------------------------------------------------------
__global__ __launch_bounds__(256)
void quanv_prep(const float* __restrict__ conv_w, // (4,1,2,2)
                const float* __restrict__ conv_b, // (4,)
                const float* __restrict__ q_w,    // (4,4) (out,in)
                const float* __restrict__ lin_w,  // (10,1568)
                const float* __restrict__ lin_b,  // (10,)
                unsigned short* __restrict__ W16, // ws
                float* __restrict__ biasOut)      // ws + 15680B
{
    const int t = threadIdx.x;

    for (int idx = blockIdx.x * 256 + t; idx < WTOT; idx += gridDim.x * 256) {
        const int o = idx / ROWLEN;
        const int j = idx - o * ROWLEN;          // pixel h*28+w
        const int h = j / 28, w = j - h * 28;
        const int p = (h >> 1) * 14 + (w >> 1);  // patch index (196)
        const int k = (h & 1) * 2 + (w & 1);     // pos in 2x2 patch
        float s = 0.f;
        #pragma unroll
        for (int c = 0; c < 4; ++c)              // conv branch
            s += conv_w[c * 4 + k] * lin_w[o * 1568 + c * 196 + p];
        #pragma unroll
        for (int q = 0; q < 4; ++q)              // quantum branch
            s += q_w[q * 4 + k] * lin_w[o * 1568 + 784 + p * 4 + q];
        // fp32 -> bf16 round-to-nearest-even
        unsigned int u = __float_as_uint(s);
        u += 0x7fffu + ((u >> 16) & 1u);
        W16[idx] = (unsigned short)(u >> 16);
    }

    if (blockIdx.x == 0) {
        __shared__ float rs[40];                 // rowsum[o][c]
        const int lane = t & 7;
        for (int pair = t >> 3; pair < 40; pair += 32) {
            const int o = pair >> 2, c = pair & 3;
            const float* base = lin_w + o * 1568 + c * 196;
            float s = 0.f;
            #pragma unroll
            for (int p = 0; p < 196; p += 8) {
                const int pp = p + lane;
                if (pp < 196) s += base[pp];
            }
            s += __shfl_xor(s, 1);
            s += __shfl_xor(s, 2);
            s += __shfl_xor(s, 4);
            if (lane == 0) rs[pair] = s;
        }
        __syncthreads();
        if (t < NOUT) {
            float s = lin_b[t];
            #pragma unroll
            for (int c = 0; c < 4; ++c) s += conv_b[c] * rs[t * 4 + c];
            biasOut[t] = s;
        }
    }
}

// ---------------------------------------------------------------------------
// Main. bf16 W in LDS (15.7 KB) -> wave-limited 6 blocks/CU, 24 waves/CU.
// Layout: 32-lane pair owns 2 adjacent rows; lower 16 lanes accumulate
// outputs 0..4, upper 16 outputs 5..9. Depth-2 prefetch on x.
// Block 256 thr = 16 rows; grid = 2048.
// ---------------------------------------------------------------------------
__global__ __launch_bounds__(256, 6)
void quanv_main(const float* __restrict__ x,
                const unsigned short* __restrict__ Wg, // ws (bf16)
                const float* __restrict__ biasG,
                float* __restrict__ out)
{
    __shared__ unsigned short Wl[WTOT];   // 15680 B
    __shared__ float bias[NOUT];

    const int t    = threadIdx.x;
    const int lane = t & 63;
    const int wv   = t >> 6;           // wave in block 0..3
    const int l    = lane & 15;        // lane in 16-group
    const int gp   = (lane >> 4) & 1;  // output-half: 0 -> 0-4, 1 -> 5-9
    const int pr   = lane >> 5;        // pair in wave 0,1
    const int r0   = blockIdx.x * 16 + wv * 4 + pr * 2;  // rows r0, r0+1

    const float* __restrict__ xr = x + (size_t)r0 * ROWLEN;

    // issue initial x prefetch BEFORE the LDS fill (independent work)
    float4 px0[2], px1[2];
    #pragma unroll
    for (int r = 0; r < 2; ++r) {
        px0[r] = *(const float4*)(xr + r * ROWLEN + 4 * l);
        px1[r] = *(const float4*)(xr + r * ROWLEN + 4 * l + 64);
    }

    {   // coalesced LDS fill: 980 uint4 (7840 ushort) over 256 threads
        const uint4* __restrict__ src = (const uint4*)Wg;
        uint4* dst = (uint4*)Wl;
        #pragma unroll
        for (int i = 0; i < 4; ++i) {            // 256*4 = 1024 >= 980
            const int idx = t + 256 * i;
            if (idx < WTOT / 8) dst[idx] = src[idx];
        }
        if (t < NOUT) bias[t] = biasG[t];
    }
    __syncthreads();

    float acc[2][5];
    #pragma unroll
    for (int r = 0; r < 2; ++r)
        #pragma unroll
        for (int o = 0; o < 5; ++o) acc[r][o] = 0.f;

    const int wb = gp * 5 * ROWLEN;    // this half's W base (elements)

    // 784 floats = 196 float4 chunks; 16 lanes -> 12 full iters + 4-chunk tail
    #pragma unroll
    for (int i = 0; i < 12; ++i) {
        float4 cur[2];
        #pragma unroll
        for (int r = 0; r < 2; ++r) cur[r] = ((i & 1) == 0) ? px0[r] : px1[r];

        const int ni = i + 2;                    // depth-2 prefetch
        if (ni < 12) {
            const int nfo = 4 * l + 64 * ni;
            #pragma unroll
            for (int r = 0; r < 2; ++r) {
                const float4 v = *(const float4*)(xr + r * ROWLEN + nfo);
                if ((i & 1) == 0) px0[r] = v; else px1[r] = v;
            }
        } else if (ni == 12) {                   // i==10 -> tail into px0
            const int tfo = 768 + 4 * (l & 3);
            #pragma unroll
            for (int r = 0; r < 2; ++r)
                px0[r] = *(const float4*)(xr + r * ROWLEN + tfo);
        }

        const int fo = 4 * l + 64 * i;
        #pragma unroll
        for (int o = 0; o < 5; ++o) {
            const uint2 wp = *(const uint2*)&Wl[wb + o * ROWLEN + fo];
            const float w0 = __uint_as_float(wp.x << 16);
            const float w1 = __uint_as_float(wp.x & 0xffff0000u);
            const float w2 = __uint_as_float(wp.y << 16);
            const float w3 = __uint_as_float(wp.y & 0xffff0000u);
            #pragma unroll
            for (int r = 0; r < 2; ++r)
                acc[r][o] = fmaf(cur[r].x, w0, fmaf(cur[r].y, w1,
                            fmaf(cur[r].z, w2, fmaf(cur[r].w, w3, acc[r][o]))));
        }
    }
    // tail: floats 768..783 (in px0, loaded at i==10); lanes 0..3 only
    if (l < 4) {
        const int fo = 768 + 4 * l;
        #pragma unroll
        for (int o = 0; o < 5; ++o) {
            const uint2 wp = *(const uint2*)&Wl[wb + o * ROWLEN + fo];
            const float w0 = __uint_as_float(wp.x << 16);
            const float w1 = __uint_as_float(wp.x & 0xffff0000u);
            const float w2 = __uint_as_float(wp.y << 16);
            const float w3 = __uint_as_float(wp.y & 0xffff0000u);
            #pragma unroll
            for (int r = 0; r < 2; ++r)
                acc[r][o] = fmaf(px0[r].x, w0, fmaf(px0[r].y, w1,
                            fmaf(px0[r].z, w2, fmaf(px0[r].w, w3, acc[r][o]))));
        }
    }

    // butterfly over the 16-lane group: full-K totals on every lane
    #pragma unroll
    for (int r = 0; r < 2; ++r)
        #pragma unroll
        for (int o = 0; o < 5; ++o) {
            acc[r][o] += __shfl_xor(acc[r][o], 1);
            acc[r][o] += __shfl_xor(acc[r][o], 2);
            acc[r][o] += __shfl_xor(acc[r][o], 4);
            acc[r][o] += __shfl_xor(acc[r][o], 8);
        }

    // add own-half bias; exchange with output-half partner (xor 16)
    float own[2][5], ex[2][5];
    #pragma unroll
    for (int r = 0; r < 2; ++r)
        #pragma unroll
        for (int o = 0; o < 5; ++o) {
            own[r][o] = acc[r][o] + bias[gp * 5 + o];
            ex[r][o]  = __shfl_xor(own[r][o], 16);
        }

    // gp=0 half finishes row r0, gp=1 half finishes row r0+1
    float lg[NOUT];
    #pragma unroll
    for (int o = 0; o < 5; ++o) {
        lg[o]     = gp ? ex[1][o]  : own[0][o];
        lg[o + 5] = gp ? own[1][o] : ex[0][o];
    }

    float m = -1e30f;
    #pragma unroll
    for (int o = 0; o < NOUT; ++o) m = fmaxf(m, lg[o]);
    float s = 0.f;
    #pragma unroll
    for (int o = 0; o < NOUT; ++o) s += expf(lg[o] - m);
    const float lse = m + logf(s);

    if (l < NOUT) {
        float v = lg[0];
        #pragma unroll
        for (int o = 1; o < NOUT; ++o) v = (l == o) ? lg[o] : v;
        out[(size_t)(r0 + gp) * NOUT + l] = v - lse;
    }
}

extern "C" void kernel_launch(void* const* d_in, const int* in_sizes, int n_in,
                              void* d_out, int out_size, void* d_ws, size_t ws_size,
                              hipStream_t stream) {
    const float* x      = (const float*)d_in[0];
    const float* conv_w = (const float*)d_in[1];
    const float* conv_b = (const float*)d_in[2];
    const float* q_w    = (const float*)d_in[3];
    const float* lin_w  = (const float*)d_in[4];
    const float* lin_b  = (const float*)d_in[5];
    float* out = (float*)d_out;

    unsigned short* W16 = (unsigned short*)d_ws;          // 7840 ushort = 15680B
    float* biasWs       = (float*)((char*)d_ws + 15680);  // 10 floats

    const int rows = in_sizes[0] / ROWLEN;   // 32768

    quanv_prep<<<31, 256, 0, stream>>>(conv_w, conv_b, q_w, lin_w, lin_b,
                                       W16, biasWs);
    quanv_main<<<rows / 16, 256, 0, stream>>>(x, W16, biasWs, out);
}